// Round 1
// baseline (59.085 us; speedup 1.0000x reference)
//
#include <hip/hip_runtime.h>
#include <math.h>

#define B_ 2
#define N_ 20000
#define M_ 1024
#define C_ 256
#define BN_EPS_ 1e-5f

// ---------------------------------------------------------------------------
// Kernel A: hidden = relu( bn_fold(W1) @ feat + bias_fold )  for both heads.
// Tiled f32 GEMM: 64(o) x 64(m) block tile, 4x4 per thread, K staged 16 wide.
// h layout: (b, head, c=256, m=1024)
// ---------------------------------------------------------------------------
__global__ __launch_bounds__(256) void k_hidden(
    const float* __restrict__ feat,
    const float* __restrict__ w1f, const float* __restrict__ b1f,
    const float* __restrict__ g1f, const float* __restrict__ be1f,
    const float* __restrict__ mu1f, const float* __restrict__ var1f,
    const float* __restrict__ w1c, const float* __restrict__ b1c,
    const float* __restrict__ g1c, const float* __restrict__ be1c,
    const float* __restrict__ mu1c, const float* __restrict__ var1c,
    float* __restrict__ h)
{
    const int mt = blockIdx.x;          // 0..15  (m tiles of 64)
    const int ot = blockIdx.y;          // 0..3   (o tiles of 64)
    const int bh = blockIdx.z;          // 0..3   b = bh>>1, head = bh&1
    const int b = bh >> 1, head = bh & 1;

    const float* __restrict__ w1   = head ? w1c   : w1f;
    const float* __restrict__ b1   = head ? b1c   : b1f;
    const float* __restrict__ g1   = head ? g1c   : g1f;
    const float* __restrict__ be1  = head ? be1c  : be1f;
    const float* __restrict__ mu1  = head ? mu1c  : mu1f;
    const float* __restrict__ var1 = head ? var1c : var1f;

    __shared__ float sW[16][68];   // [c][o], pad 68 -> 2-way max on writes, 16B-aligned rows
    __shared__ float sF[16][64];   // [c][m]

    const int tid = threadIdx.x;
    const int tm = tid & 15;       // m group (x4)
    const int to = tid >> 4;       // o group (x4)
    const int m0 = mt * 64, o0 = ot * 64;

    // staging roles
    const int so  = tid >> 2;           // w row 0..63
    const int sc4 = (tid & 3) << 2;     // w col chunk 0,4,8,12
    const float sscale = g1[o0 + so] * rsqrtf(var1[o0 + so] + BN_EPS_);
    const int fc = tid >> 4;            // feat row 0..15
    const int fm = (tid & 15) << 2;     // feat col chunk

    float acc[4][4] = {};

    for (int c0 = 0; c0 < C_; c0 += 16) {
        __syncthreads();
        float4 wv = *(const float4*)&w1[(size_t)(o0 + so) * C_ + c0 + sc4];
        sW[sc4 + 0][so] = wv.x * sscale;
        sW[sc4 + 1][so] = wv.y * sscale;
        sW[sc4 + 2][so] = wv.z * sscale;
        sW[sc4 + 3][so] = wv.w * sscale;
        *(float4*)&sF[fc][fm] =
            *(const float4*)&feat[((size_t)b * C_ + c0 + fc) * M_ + m0 + fm];
        __syncthreads();
        #pragma unroll
        for (int cc = 0; cc < 16; ++cc) {
            float4 w4 = *(const float4*)&sW[cc][to << 2];
            float4 f4 = *(const float4*)&sF[cc][tm << 2];
            float wr[4] = {w4.x, w4.y, w4.z, w4.w};
            float fr[4] = {f4.x, f4.y, f4.z, f4.w};
            #pragma unroll
            for (int i = 0; i < 4; ++i)
                #pragma unroll
                for (int j = 0; j < 4; ++j)
                    acc[i][j] = fmaf(wr[i], fr[j], acc[i][j]);
        }
    }

    #pragma unroll
    for (int i = 0; i < 4; ++i) {
        const int o = o0 + (to << 2) + i;
        const float sc = g1[o] * rsqrtf(var1[o] + BN_EPS_);
        const float bb = (b1[o] - mu1[o]) * sc + be1[o];
        float4 r;
        r.x = fmaxf(acc[i][0] + bb, 0.f);
        r.y = fmaxf(acc[i][1] + bb, 0.f);
        r.z = fmaxf(acc[i][2] + bb, 0.f);
        r.w = fmaxf(acc[i][3] + bb, 0.f);
        *(float4*)&h[(((size_t)(b * 2 + head)) * C_ + o) * M_ + m0 + (tm << 2)] = r;
    }
}

// ---------------------------------------------------------------------------
// Kernel B: out5[b][j][m] = w2_row_j . h[b,head(j),:,m] + b2_j
// j 0..1 -> fg head (w2f), j 2..4 -> co head (w2c)
// ---------------------------------------------------------------------------
__global__ __launch_bounds__(256) void k_out5(
    const float* __restrict__ h,
    const float* __restrict__ w2f, const float* __restrict__ b2f,
    const float* __restrict__ w2c, const float* __restrict__ b2c,
    float* __restrict__ out5)
{
    const int m = (blockIdx.x << 8) + threadIdx.x;
    const int j = blockIdx.y;
    const int b = blockIdx.z;
    const int head = (j < 2) ? 0 : 1;
    const float* __restrict__ w2 = (j < 2) ? (w2f + j * C_) : (w2c + (j - 2) * C_);
    const float bias = (j < 2) ? b2f[j] : b2c[j - 2];

    __shared__ float sw[C_];
    sw[threadIdx.x] = w2[threadIdx.x];
    __syncthreads();

    const float* __restrict__ hp = h + ((size_t)(b * 2 + head) * C_) * M_ + m;
    float acc = bias;
    #pragma unroll 8
    for (int c = 0; c < C_; ++c)
        acc = fmaf(sw[c], hp[(size_t)c * M_], acc);
    out5[((size_t)b * 5 + j) * M_ + m] = acc;
}

// ---------------------------------------------------------------------------
// Kernel C: brute-force 3-NN (matching ref's |u|^2+|k|^2-2u.k formula) fused
// with inverse-distance interpolation of out5.
// Block: 256 threads = 4 waves; 64 points per block (lane = point).
// Each wave scans a 256-seed quarter keeping a sorted top-3; merge via LDS.
// ---------------------------------------------------------------------------
#define INSERT3(dd, ss)                                   \
    {                                                     \
        bool c2_ = (dd) < v2;                             \
        v2 = c2_ ? (dd) : v2;  i2 = c2_ ? (ss) : i2;      \
        bool c1_ = v2 < v1;                               \
        float tv_ = v1; int ti_ = i1;                     \
        v1 = c1_ ? v2 : v1;  i1 = c1_ ? i2 : i1;          \
        v2 = c1_ ? tv_ : v2; i2 = c1_ ? ti_ : i2;         \
        bool c0_ = v1 < v0;                               \
        tv_ = v0; ti_ = i0;                               \
        v0 = c0_ ? v1 : v0;  i0 = c0_ ? i1 : i0;          \
        v1 = c0_ ? tv_ : v1; i1 = c0_ ? ti_ : i1;         \
    }

__global__ __launch_bounds__(256) void k_nn_interp(
    const float* __restrict__ pc, const float* __restrict__ seed,
    const float* __restrict__ out5, float* __restrict__ out)
{
    const int b = blockIdx.y;
    const int p0 = blockIdx.x << 6;
    const int tid = threadIdx.x;
    const int wv = tid >> 6, lane = tid & 63;

    __shared__ float4 sseed[M_];
    __shared__ float smd[4][64][3];
    __shared__ int   smi[4][64][3];

    for (int s = tid; s < M_; s += 256) {
        const float kx = seed[((size_t)b * M_ + s) * 3 + 0];
        const float ky = seed[((size_t)b * M_ + s) * 3 + 1];
        const float kz = seed[((size_t)b * M_ + s) * 3 + 2];
        sseed[s] = make_float4(kx, ky, kz, (kx * kx + ky * ky) + kz * kz);
    }
    __syncthreads();

    const int p = p0 + lane;
    const int pcl = (p < N_) ? p : (N_ - 1);
    const float ux = pc[((size_t)b * N_ + pcl) * 3 + 0];
    const float uy = pc[((size_t)b * N_ + pcl) * 3 + 1];
    const float uz = pc[((size_t)b * N_ + pcl) * 3 + 2];
    const float un = (ux * ux + uy * uy) + uz * uz;

    float v0 = 3.4e38f, v1 = 3.4e38f, v2 = 3.4e38f;
    int i0 = 0, i1 = 0, i2 = 0;
    const int sb = wv << 8;
    #pragma unroll 8
    for (int t = 0; t < 256; ++t) {
        const float4 k = sseed[sb + t];
        const float dot = fmaf(ux, k.x, fmaf(uy, k.y, uz * k.z));
        const float d2 = (un + k.w) - 2.0f * dot;   // exact ref formula order
        INSERT3(d2, sb + t);
    }

    smd[wv][lane][0] = v0; smd[wv][lane][1] = v1; smd[wv][lane][2] = v2;
    smi[wv][lane][0] = i0; smi[wv][lane][1] = i1; smi[wv][lane][2] = i2;
    __syncthreads();

    if (wv == 0) {
        #pragma unroll
        for (int w = 1; w < 4; ++w) {
            #pragma unroll
            for (int k = 0; k < 3; ++k) {
                const float dd = smd[w][lane][k];
                const int   ss = smi[w][lane][k];
                INSERT3(dd, ss);
            }
        }
        const float d0 = sqrtf(fmaxf(v0, 1e-12f));
        const float d1 = sqrtf(fmaxf(v1, 1e-12f));
        const float d2s = sqrtf(fmaxf(v2, 1e-12f));
        const float r0 = 1.f / (d0 + 1e-8f);
        const float r1 = 1.f / (d1 + 1e-8f);
        const float r2 = 1.f / (d2s + 1e-8f);
        const float rs = (r0 + r1) + r2;
        const float q0 = r0 / rs, q1 = r1 / rs, q2 = r2 / rs;
        if (p < N_) {
            #pragma unroll
            for (int j = 0; j < 5; ++j) {
                const float* __restrict__ o5 = out5 + ((size_t)b * 5 + j) * M_;
                const float val = fmaf(q0, o5[i0], fmaf(q1, o5[i1], q2 * o5[i2]));
                out[((size_t)b * 5 + j) * N_ + p] = val;
            }
        }
    }
}

// ---------------------------------------------------------------------------
extern "C" void kernel_launch(void* const* d_in, const int* in_sizes, int n_in,
                              void* d_out, int out_size, void* d_ws, size_t ws_size,
                              hipStream_t stream)
{
    const float* pc    = (const float*)d_in[0];
    const float* sxyz  = (const float*)d_in[1];
    const float* feat  = (const float*)d_in[2];
    const float* w1f   = (const float*)d_in[3];
    const float* b1f   = (const float*)d_in[4];
    const float* g1f   = (const float*)d_in[5];
    const float* be1f  = (const float*)d_in[6];
    const float* mu1f  = (const float*)d_in[7];
    const float* var1f = (const float*)d_in[8];
    const float* w2f   = (const float*)d_in[9];
    const float* b2f   = (const float*)d_in[10];
    const float* w1c   = (const float*)d_in[11];
    const float* b1c   = (const float*)d_in[12];
    const float* g1c   = (const float*)d_in[13];
    const float* be1c  = (const float*)d_in[14];
    const float* mu1c  = (const float*)d_in[15];
    const float* var1c = (const float*)d_in[16];
    const float* w2c   = (const float*)d_in[17];
    const float* b2c   = (const float*)d_in[18];

    float* out  = (float*)d_out;
    float* h    = (float*)d_ws;                        // B*2*C*M = 1,048,576 f32
    float* out5 = h + (size_t)B_ * 2 * C_ * M_;        // B*5*M   = 10,240 f32

    k_hidden<<<dim3(16, 4, 4), 256, 0, stream>>>(
        feat, w1f, b1f, g1f, be1f, mu1f, var1f,
        w1c, b1c, g1c, be1c, mu1c, var1c, h);

    k_out5<<<dim3(4, 5, 2), 256, 0, stream>>>(h, w2f, b2f, w2c, b2c, out5);

    k_nn_interp<<<dim3((N_ + 63) / 64, B_), 256, 0, stream>>>(pc, sxyz, out5, out);
}

// Round 2
// 43.752 us; speedup vs baseline: 1.3505x; 1.3505x over previous
//
#include <hip/hip_runtime.h>
#include <math.h>

#define B_ 2
#define N_ 20000
#define M_ 1024
#define C_ 256
#define BN_EPS_ 1e-5f

// ---------------------------------------------------------------------------
// Kernel 1: fused  out5_partial[ot] = W2 @ relu( bn_fold(W1) @ feat + b )
// 64(o) x 64(m) block tile, 4x4 per thread, K staged 16 wide, reg-prefetch.
// Partials: part[ot][b][j][m] (j=0..4; head0 -> j 0,1; head1 -> j 2,3,4),
// each slot written by exactly one block -> deterministic, no init needed.
// ---------------------------------------------------------------------------
__global__ __launch_bounds__(256) void k_head(
    const float* __restrict__ feat,
    const float* __restrict__ w1f, const float* __restrict__ b1f,
    const float* __restrict__ g1f, const float* __restrict__ be1f,
    const float* __restrict__ mu1f, const float* __restrict__ var1f,
    const float* __restrict__ w2f, const float* __restrict__ b2f,
    const float* __restrict__ w1c, const float* __restrict__ b1c,
    const float* __restrict__ g1c, const float* __restrict__ be1c,
    const float* __restrict__ mu1c, const float* __restrict__ var1c,
    const float* __restrict__ w2c, const float* __restrict__ b2c,
    float* __restrict__ part)
{
    const int mt = blockIdx.x;          // 0..15
    const int ot = blockIdx.y;          // 0..3
    const int bh = blockIdx.z;          // 0..3
    const int b = bh >> 1, head = bh & 1;

    const float* __restrict__ w1   = head ? w1c   : w1f;
    const float* __restrict__ b1   = head ? b1c   : b1f;
    const float* __restrict__ g1   = head ? g1c   : g1f;
    const float* __restrict__ be1  = head ? be1c  : be1f;
    const float* __restrict__ mu1  = head ? mu1c  : mu1f;
    const float* __restrict__ var1 = head ? var1c : var1f;
    const float* __restrict__ w2   = head ? w2c   : w2f;
    const float* __restrict__ b2   = head ? b2c   : b2f;
    const int nj = head ? 3 : 2;

    __shared__ float sW[16][68];        // [c][o]
    __shared__ float sF[16][64];        // [c][m]
    __shared__ float sred[16][3][68];   // [to][j][m], padded stride

    const int tid = threadIdx.x;
    const int tm = tid & 15;
    const int to = tid >> 4;
    const int m0 = mt * 64, o0 = ot * 64;

    const int so  = tid >> 2;
    const int sc4 = (tid & 3) << 2;
    const float sscale = g1[o0 + so] * rsqrtf(var1[o0 + so] + BN_EPS_);
    const int fc = tid >> 4;
    const int fm = (tid & 15) << 2;

    const float* __restrict__ wrow = w1 + (size_t)(o0 + so) * C_ + sc4;
    const float* __restrict__ frow = feat + ((size_t)b * C_ + fc) * M_ + m0 + fm;

    float4 wv = *(const float4*)(wrow);
    float4 fv = *(const float4*)(frow);

    float acc[4][4] = {};

    for (int c0 = 0; c0 < C_; c0 += 16) {
        __syncthreads();                 // previous compute done
        sW[sc4 + 0][so] = wv.x * sscale;
        sW[sc4 + 1][so] = wv.y * sscale;
        sW[sc4 + 2][so] = wv.z * sscale;
        sW[sc4 + 3][so] = wv.w * sscale;
        *(float4*)&sF[fc][fm] = fv;
        __syncthreads();                 // LDS ready
        const int cn = (c0 + 16 < C_) ? c0 + 16 : c0;   // last iter: harmless reload
        wv = *(const float4*)(wrow + cn);
        fv = *(const float4*)(frow + (size_t)cn * M_);
        #pragma unroll
        for (int cc = 0; cc < 16; ++cc) {
            float4 w4 = *(const float4*)&sW[cc][to << 2];
            float4 f4 = *(const float4*)&sF[cc][tm << 2];
            float wr[4] = {w4.x, w4.y, w4.z, w4.w};
            float fr[4] = {f4.x, f4.y, f4.z, f4.w};
            #pragma unroll
            for (int i = 0; i < 4; ++i)
                #pragma unroll
                for (int j = 0; j < 4; ++j)
                    acc[i][j] = fmaf(wr[i], fr[j], acc[i][j]);
        }
    }

    // relu(bias + acc) in registers
    float r[4][4];
    #pragma unroll
    for (int i = 0; i < 4; ++i) {
        const int o = o0 + (to << 2) + i;
        const float sc = g1[o] * rsqrtf(var1[o] + BN_EPS_);
        const float bb = (b1[o] - mu1[o]) * sc + be1[o];
        #pragma unroll
        for (int jj = 0; jj < 4; ++jj)
            r[i][jj] = fmaxf(acc[i][jj] + bb, 0.f);
    }

    __syncthreads();                     // sF compute consumers done (reuse phase)
    // per-thread w2 partial over this thread's 4 o-channels
    for (int j = 0; j < nj; ++j) {
        float s[4] = {0.f, 0.f, 0.f, 0.f};
        #pragma unroll
        for (int i = 0; i < 4; ++i) {
            const float w = w2[(size_t)j * C_ + o0 + (to << 2) + i];
            #pragma unroll
            for (int jj = 0; jj < 4; ++jj)
                s[jj] = fmaf(w, r[i][jj], s[jj]);
        }
        *(float4*)&sred[to][j][tm << 2] = *(float4*)s;
    }
    __syncthreads();

    // reduce over the 16 to-groups: nj*64 values
    if (tid < nj * 64) {
        const int j = tid >> 6, m = tid & 63;
        float a = 0.f;
        #pragma unroll
        for (int t = 0; t < 16; ++t) a += sred[t][j][m];
        if (ot == 0) a += b2[j];
        const int jg = head ? (2 + j) : j;
        part[(((size_t)ot * B_ + b) * 5 + jg) * M_ + m0 + m] = a;
    }
}

// ---------------------------------------------------------------------------
// Kernel 2: brute-force 3-NN fused with interpolation.
// 512 threads = 8 waves; 64 points/block (lane = point); wave w scans the
// 128-seed slice [128w, 128w+128). Selection metric t = 0.5|k|^2 - u.k
// (monotonic in d2 = 2t + |u|^2). out5 partials pre-summed into LDS.
// ---------------------------------------------------------------------------
#define INSERT3(dd, ss)                                   \
    {                                                     \
        bool c2_ = (dd) < v2;                             \
        v2 = c2_ ? (dd) : v2;  i2 = c2_ ? (ss) : i2;      \
        bool c1_ = v2 < v1;                               \
        float tv_ = v1; int ti_ = i1;                     \
        v1 = c1_ ? v2 : v1;  i1 = c1_ ? i2 : i1;          \
        v2 = c1_ ? tv_ : v2; i2 = c1_ ? ti_ : i2;         \
        bool c0_ = v1 < v0;                               \
        tv_ = v0; ti_ = i0;                               \
        v0 = c0_ ? v1 : v0;  i0 = c0_ ? i1 : i0;          \
        v1 = c0_ ? tv_ : v1; i1 = c0_ ? ti_ : i1;         \
    }

__global__ __launch_bounds__(512) void k_nn_interp(
    const float* __restrict__ pc, const float* __restrict__ seed,
    const float* __restrict__ part, float* __restrict__ out)
{
    const int b = blockIdx.y;
    const int p0 = blockIdx.x << 6;
    const int tid = threadIdx.x;
    const int wv = tid >> 6, lane = tid & 63;

    __shared__ float4 sseed[M_];
    __shared__ float so5[5][M_];
    __shared__ float smd[8][64][3];
    __shared__ int   smi[8][64][3];

    for (int s = tid; s < M_; s += 512) {
        const float kx = seed[((size_t)b * M_ + s) * 3 + 0];
        const float ky = seed[((size_t)b * M_ + s) * 3 + 1];
        const float kz = seed[((size_t)b * M_ + s) * 3 + 2];
        sseed[s] = make_float4(kx, ky, kz, 0.5f * ((kx * kx + ky * ky) + kz * kz));
    }
    for (int v = tid; v < 5 * M_; v += 512) {
        const int j = v >> 10, m = v & (M_ - 1);
        const float* __restrict__ pp = part + ((size_t)b * 5 + j) * M_ + m;
        so5[j][m] = ((pp[0] + pp[10240]) + (pp[20480] + pp[30720]));
    }
    __syncthreads();

    const int p = p0 + lane;
    const int pcl = (p < N_) ? p : (N_ - 1);
    const float ux = pc[((size_t)b * N_ + pcl) * 3 + 0];
    const float uy = pc[((size_t)b * N_ + pcl) * 3 + 1];
    const float uz = pc[((size_t)b * N_ + pcl) * 3 + 2];
    const float un = (ux * ux + uy * uy) + uz * uz;

    float v0 = 3.4e38f, v1 = 3.4e38f, v2 = 3.4e38f;
    int i0 = 0, i1 = 0, i2 = 0;
    const int sb = wv << 7;
    #pragma unroll 8
    for (int t = 0; t < 128; ++t) {
        const float4 k = sseed[sb + t];
        // t = 0.5|k|^2 - u.k   (3 FMA; order preserved vs d2 = 2t + |u|^2)
        const float d = fmaf(-ux, k.x, fmaf(-uy, k.y, fmaf(-uz, k.z, k.w)));
        INSERT3(d, sb + t);
    }

    smd[wv][lane][0] = v0; smd[wv][lane][1] = v1; smd[wv][lane][2] = v2;
    smi[wv][lane][0] = i0; smi[wv][lane][1] = i1; smi[wv][lane][2] = i2;
    __syncthreads();

    if (wv == 0 && p < N_) {
        #pragma unroll
        for (int w = 1; w < 8; ++w) {
            #pragma unroll
            for (int k = 0; k < 3; ++k) {
                const float dd = smd[w][lane][k];
                const int   ss = smi[w][lane][k];
                INSERT3(dd, ss);
            }
        }
        const float d0 = sqrtf(fmaxf(fmaf(2.f, v0, un), 1e-12f));
        const float d1 = sqrtf(fmaxf(fmaf(2.f, v1, un), 1e-12f));
        const float d2s = sqrtf(fmaxf(fmaf(2.f, v2, un), 1e-12f));
        const float r0 = 1.f / (d0 + 1e-8f);
        const float r1 = 1.f / (d1 + 1e-8f);
        const float r2 = 1.f / (d2s + 1e-8f);
        const float rs = (r0 + r1) + r2;
        const float q0 = r0 / rs, q1 = r1 / rs, q2 = r2 / rs;
        #pragma unroll
        for (int j = 0; j < 5; ++j) {
            const float val = fmaf(q0, so5[j][i0], fmaf(q1, so5[j][i1], q2 * so5[j][i2]));
            out[((size_t)b * 5 + j) * N_ + p] = val;
        }
    }
}

// ---------------------------------------------------------------------------
extern "C" void kernel_launch(void* const* d_in, const int* in_sizes, int n_in,
                              void* d_out, int out_size, void* d_ws, size_t ws_size,
                              hipStream_t stream)
{
    const float* pc    = (const float*)d_in[0];
    const float* sxyz  = (const float*)d_in[1];
    const float* feat  = (const float*)d_in[2];
    const float* w1f   = (const float*)d_in[3];
    const float* b1f   = (const float*)d_in[4];
    const float* g1f   = (const float*)d_in[5];
    const float* be1f  = (const float*)d_in[6];
    const float* mu1f  = (const float*)d_in[7];
    const float* var1f = (const float*)d_in[8];
    const float* w2f   = (const float*)d_in[9];
    const float* b2f   = (const float*)d_in[10];
    const float* w1c   = (const float*)d_in[11];
    const float* b1c   = (const float*)d_in[12];
    const float* g1c   = (const float*)d_in[13];
    const float* be1c  = (const float*)d_in[14];
    const float* mu1c  = (const float*)d_in[15];
    const float* var1c = (const float*)d_in[16];
    const float* w2c   = (const float*)d_in[17];
    const float* b2c   = (const float*)d_in[18];

    float* out  = (float*)d_out;
    float* part = (float*)d_ws;          // [4 ot][2 b][5 j][1024 m] f32 = 160 KB

    k_head<<<dim3(16, 4, 4), 256, 0, stream>>>(
        feat, w1f, b1f, g1f, be1f, mu1f, var1f, w2f, b2f,
        w1c, b1c, g1c, be1c, mu1c, var1c, w2c, b2c, part);

    k_nn_interp<<<dim3((N_ + 63) / 64, B_), 512, 0, stream>>>(pc, sxyz, part, out);
}

// Round 5
// 36.968 us; speedup vs baseline: 1.5983x; 1.1835x over previous
//
#include <hip/hip_runtime.h>
#include <math.h>

#define B_ 2
#define N_ 20000
#define M_ 1024
#define C_ 256
#define BN_EPS_ 1e-5f

#define NNBLK_PER_B_ 313            // ceil(20000/64)
#define GEMM_BLOCKS_ 256            // 16 mt x 4 ot x 4 bh
#define NN_BLOCKS_   (2 * NNBLK_PER_B_)

// index-carrying sorted top-3 insert, strict < keeps earliest (lowest index)
#define INSERT3(dd, ss)                                   \
    {                                                     \
        bool c2_ = (dd) < v2;                             \
        v2 = c2_ ? (dd) : v2;  i2 = c2_ ? (ss) : i2;      \
        bool c1_ = v2 < v1;                               \
        float tv_ = v1; int ti_ = i1;                     \
        v1 = c1_ ? v2 : v1;  i1 = c1_ ? i2 : i1;          \
        v2 = c1_ ? tv_ : v2; i2 = c1_ ? ti_ : i2;         \
        bool c0_ = v1 < v0;                               \
        tv_ = v0; ti_ = i0;                               \
        v0 = c0_ ? v1 : v0;  i0 = c0_ ? i1 : i0;          \
        v1 = c0_ ? tv_ : v1; i1 = c0_ ? ti_ : i1;         \
    }

// ---------------------------------------------------------------------------
// Fused kernel: blocks [0,256) run the head GEMMs -> part[],
//               blocks [256,882) run 3-NN -> nnres[] (packed idx + weights).
// NN math is the round-2-proven path verbatim (explicit index carry).
// ---------------------------------------------------------------------------
__global__ __launch_bounds__(256) void k_fused(
    const float* __restrict__ pc, const float* __restrict__ seed,
    const float* __restrict__ feat,
    const float* __restrict__ w1f, const float* __restrict__ b1f,
    const float* __restrict__ g1f, const float* __restrict__ be1f,
    const float* __restrict__ mu1f, const float* __restrict__ var1f,
    const float* __restrict__ w2f, const float* __restrict__ b2f,
    const float* __restrict__ w1c, const float* __restrict__ b1c,
    const float* __restrict__ g1c, const float* __restrict__ be1c,
    const float* __restrict__ mu1c, const float* __restrict__ var1c,
    const float* __restrict__ w2c, const float* __restrict__ b2c,
    float* __restrict__ part, uint4* __restrict__ nnres)
{
    __shared__ float4 smembuf[1408];          // 22528 B, union of both roles
    const int bid = blockIdx.x;
    const int tid = threadIdx.x;

    if (bid < GEMM_BLOCKS_) {
        // =================== GEMM role (round-2 proven) ===================
        const int mt = bid & 15;
        const int ot = (bid >> 4) & 3;
        const int bh = bid >> 6;
        const int b = bh >> 1, head = bh & 1;

        const float* __restrict__ w1   = head ? w1c   : w1f;
        const float* __restrict__ b1   = head ? b1c   : b1f;
        const float* __restrict__ g1   = head ? g1c   : g1f;
        const float* __restrict__ be1  = head ? be1c  : be1f;
        const float* __restrict__ mu1  = head ? mu1c  : mu1f;
        const float* __restrict__ var1 = head ? var1c : var1f;
        const float* __restrict__ w2   = head ? w2c   : w2f;
        const float* __restrict__ b2   = head ? b2c   : b2f;
        const int nj = head ? 3 : 2;

        float* base = (float*)smembuf;
        float (*sW)[68]      = (float(*)[68])base;             // 16x68
        float (*sF)[64]      = (float(*)[64])(base + 1088);    // 16x64
        float (*sred)[3][68] = (float(*)[3][68])(base + 2112); // 16x3x68

        const int tm = tid & 15;
        const int to = tid >> 4;
        const int m0 = mt * 64, o0 = ot * 64;

        const int so  = tid >> 2;
        const int sc4 = (tid & 3) << 2;
        const float sscale = g1[o0 + so] * rsqrtf(var1[o0 + so] + BN_EPS_);
        const int fc = tid >> 4;
        const int fm = (tid & 15) << 2;

        const float* __restrict__ wrow = w1 + (size_t)(o0 + so) * C_ + sc4;
        const float* __restrict__ frow = feat + ((size_t)b * C_ + fc) * M_ + m0 + fm;

        float4 wv = *(const float4*)(wrow);
        float4 fv = *(const float4*)(frow);

        float acc[4][4] = {};

        for (int c0 = 0; c0 < C_; c0 += 16) {
            __syncthreads();
            sW[sc4 + 0][so] = wv.x * sscale;
            sW[sc4 + 1][so] = wv.y * sscale;
            sW[sc4 + 2][so] = wv.z * sscale;
            sW[sc4 + 3][so] = wv.w * sscale;
            *(float4*)&sF[fc][fm] = fv;
            __syncthreads();
            const int cn = (c0 + 16 < C_) ? c0 + 16 : c0;
            wv = *(const float4*)(wrow + cn);
            fv = *(const float4*)(frow + (size_t)cn * M_);
            #pragma unroll
            for (int cc = 0; cc < 16; ++cc) {
                float4 w4 = *(const float4*)&sW[cc][to << 2];
                float4 f4 = *(const float4*)&sF[cc][tm << 2];
                float wr[4] = {w4.x, w4.y, w4.z, w4.w};
                float fr[4] = {f4.x, f4.y, f4.z, f4.w};
                #pragma unroll
                for (int i = 0; i < 4; ++i)
                    #pragma unroll
                    for (int j = 0; j < 4; ++j)
                        acc[i][j] = fmaf(wr[i], fr[j], acc[i][j]);
            }
        }

        float r[4][4];
        #pragma unroll
        for (int i = 0; i < 4; ++i) {
            const int o = o0 + (to << 2) + i;
            const float sc = g1[o] * rsqrtf(var1[o] + BN_EPS_);
            const float bb = (b1[o] - mu1[o]) * sc + be1[o];
            #pragma unroll
            for (int jj = 0; jj < 4; ++jj)
                r[i][jj] = fmaxf(acc[i][jj] + bb, 0.f);
        }

        __syncthreads();
        for (int j = 0; j < nj; ++j) {
            float s[4] = {0.f, 0.f, 0.f, 0.f};
            #pragma unroll
            for (int i = 0; i < 4; ++i) {
                const float w = w2[(size_t)j * C_ + o0 + (to << 2) + i];
                #pragma unroll
                for (int jj = 0; jj < 4; ++jj)
                    s[jj] = fmaf(w, r[i][jj], s[jj]);
            }
            *(float4*)&sred[to][j][tm << 2] = *(float4*)s;
        }
        __syncthreads();

        if (tid < nj * 64) {
            const int j = tid >> 6, m = tid & 63;
            float a = 0.f;
            #pragma unroll
            for (int t = 0; t < 16; ++t) a += sred[t][j][m];
            if (ot == 0) a += b2[j];
            const int jg = head ? (2 + j) : j;
            part[(((size_t)ot * B_ + b) * 5 + jg) * M_ + m0 + m] = a;
        }
    } else {
        // =================== NN role (round-2 math verbatim) ===================
        const int nb = bid - GEMM_BLOCKS_;
        const int b = (nb >= NNBLK_PER_B_) ? 1 : 0;
        const int p0 = (nb - b * NNBLK_PER_B_) << 6;
        const int wv = tid >> 6, lane = tid & 63;

        float4* sseed = smembuf;                                  // 1024 x 16B
        float* nnb = (float*)(smembuf + M_);
        float (*smd)[64][3] = (float(*)[64][3])nnb;               // 4x64x3
        int   (*smi)[64][3] = (int(*)[64][3])(nnb + 768);

        for (int s = tid; s < M_; s += 256) {
            const float kx = seed[((size_t)b * M_ + s) * 3 + 0];
            const float ky = seed[((size_t)b * M_ + s) * 3 + 1];
            const float kz = seed[((size_t)b * M_ + s) * 3 + 2];
            sseed[s] = make_float4(kx, ky, kz, 0.5f * ((kx * kx + ky * ky) + kz * kz));
        }
        __syncthreads();

        const int p = p0 + lane;
        const int pcl = (p < N_) ? p : (N_ - 1);
        const float ux = pc[((size_t)b * N_ + pcl) * 3 + 0];
        const float uy = pc[((size_t)b * N_ + pcl) * 3 + 1];
        const float uz = pc[((size_t)b * N_ + pcl) * 3 + 2];
        const float un = (ux * ux + uy * uy) + uz * uz;

        float v0 = 3.4e38f, v1 = 3.4e38f, v2 = 3.4e38f;
        int i0 = 0, i1 = 0, i2 = 0;
        const int sb = wv << 8;
        const float4* __restrict__ sp = sseed + sb;
        #pragma unroll 8
        for (int t = 0; t < 256; ++t) {
            const float4 k = sp[t];
            // t-metric = 0.5|k|^2 - u.k  (monotone in d2 = 2t + |u|^2)
            const float d = fmaf(-ux, k.x, fmaf(-uy, k.y, fmaf(-uz, k.z, k.w)));
            INSERT3(d, sb + t);
        }

        smd[wv][lane][0] = v0; smd[wv][lane][1] = v1; smd[wv][lane][2] = v2;
        smi[wv][lane][0] = i0; smi[wv][lane][1] = i1; smi[wv][lane][2] = i2;
        __syncthreads();

        if (wv == 0 && p < N_) {
            #pragma unroll
            for (int w = 1; w < 4; ++w) {
                #pragma unroll
                for (int k = 0; k < 3; ++k) {
                    const float dd = smd[w][lane][k];
                    const int   ss = smi[w][lane][k];
                    INSERT3(dd, ss);
                }
            }
            const float d0 = sqrtf(fmaxf(fmaf(2.f, v0, un), 1e-12f));
            const float d1 = sqrtf(fmaxf(fmaf(2.f, v1, un), 1e-12f));
            const float d2s = sqrtf(fmaxf(fmaf(2.f, v2, un), 1e-12f));
            const float r0 = 1.f / (d0 + 1e-8f);
            const float r1 = 1.f / (d1 + 1e-8f);
            const float r2 = 1.f / (d2s + 1e-8f);
            const float rs = (r0 + r1) + r2;
            const float q0 = r0 / rs, q1 = r1 / rs, q2 = r2 / rs;
            const unsigned pk = (unsigned)i0 | ((unsigned)i1 << 10) | ((unsigned)i2 << 20);
            nnres[(size_t)b * N_ + p] = make_uint4(
                pk, __float_as_uint(q0), __float_as_uint(q1), __float_as_uint(q2));
        }
    }
}

// ---------------------------------------------------------------------------
// Gather epilogue: out[b][j][p] = sum_k q_k * so5[j][idx_k]
// ---------------------------------------------------------------------------
__global__ __launch_bounds__(256) void k_gather(
    const float* __restrict__ part, const uint4* __restrict__ nnres,
    float* __restrict__ out)
{
    const int b = blockIdx.y;
    __shared__ float so5[5][M_];
    for (int v = threadIdx.x; v < 5 * M_; v += 256) {
        const int j = v >> 10, m = v & (M_ - 1);
        const float* __restrict__ pp = part + ((size_t)b * 5 + j) * M_ + m;
        so5[j][m] = (pp[0] + pp[10240]) + (pp[20480] + pp[30720]);
    }
    __syncthreads();

    const int p = (blockIdx.x << 8) + threadIdx.x;
    if (p < N_) {
        const uint4 r = nnres[(size_t)b * N_ + p];
        const int i0 = r.x & 1023, i1 = (r.x >> 10) & 1023, i2 = (r.x >> 20) & 1023;
        const float q0 = __uint_as_float(r.y);
        const float q1 = __uint_as_float(r.z);
        const float q2 = __uint_as_float(r.w);
        #pragma unroll
        for (int j = 0; j < 5; ++j) {
            out[((size_t)b * 5 + j) * N_ + p] =
                fmaf(q0, so5[j][i0], fmaf(q1, so5[j][i1], q2 * so5[j][i2]));
        }
    }
}

// ---------------------------------------------------------------------------
extern "C" void kernel_launch(void* const* d_in, const int* in_sizes, int n_in,
                              void* d_out, int out_size, void* d_ws, size_t ws_size,
                              hipStream_t stream)
{
    const float* pc    = (const float*)d_in[0];
    const float* sxyz  = (const float*)d_in[1];
    const float* feat  = (const float*)d_in[2];
    const float* w1f   = (const float*)d_in[3];
    const float* b1f   = (const float*)d_in[4];
    const float* g1f   = (const float*)d_in[5];
    const float* be1f  = (const float*)d_in[6];
    const float* mu1f  = (const float*)d_in[7];
    const float* var1f = (const float*)d_in[8];
    const float* w2f   = (const float*)d_in[9];
    const float* b2f   = (const float*)d_in[10];
    const float* w1c   = (const float*)d_in[11];
    const float* b1c   = (const float*)d_in[12];
    const float* g1c   = (const float*)d_in[13];
    const float* be1c  = (const float*)d_in[14];
    const float* mu1c  = (const float*)d_in[15];
    const float* var1c = (const float*)d_in[16];
    const float* w2c   = (const float*)d_in[17];
    const float* b2c   = (const float*)d_in[18];

    float* out  = (float*)d_out;
    float* part = (float*)d_ws;                         // 4*2*5*1024 f32 = 160 KB
    uint4* nnres = (uint4*)((char*)d_ws + 163840);      // 40000 * 16 B

    k_fused<<<dim3(GEMM_BLOCKS_ + NN_BLOCKS_), 256, 0, stream>>>(
        pc, sxyz, feat,
        w1f, b1f, g1f, be1f, mu1f, var1f, w2f, b2f,
        w1c, b1c, g1c, be1c, mu1c, var1c, w2c, b2c,
        part, nnres);

    k_gather<<<dim3((N_ + 255) / 256, B_), 256, 0, stream>>>(part, nnres, out);
}